// Round 8
// baseline (302.082 us; speedup 1.0000x reference)
//
#include <hip/hip_runtime.h>

// GraphSAGE 2-layer + edge scorer, MI355X.
// R8: gather1 XCD-locality fix. x/agg1 stored column-blocked:
// xcb[blk][node][16], blk in [0,8) -- each 16-col slice is 1.6 MB and fits a
// single XCD's 4 MB L2. gather1 uses cblk = blockIdx%8 so (with round-robin
// block->XCD dispatch) each XCD streams edges against only its own slice,
// cutting the 8x table re-fetch (~90 MB) to ~40 MB. gemm1 A-frags read the
// column-blocked layout directly. convx+convw merged into one kernel.
// Kept: scalar gather2 via wp-dot commute (R7), binned CSR build (R6),
// B-in-registers GEMMs (R5), mean(h1[src])@W2n == mean((h1@W2n)[src]).

#define NN 50000
#define EM 800000
#define EPOS 200000
#define ENEG 200000
#define NB 196            // scan blocks / coarse buckets: 196*256 >= NN
#define RPB 4096          // records per bin_kernel block
#define MTILES 3125       // 50000 / 16 exactly
#define GEMM_GRID 512
#define XCONV_BLOCKS 6250 // NN*128/4/256

typedef __bf16 bf16;
typedef bf16 bf16x2 __attribute__((ext_vector_type(2)));
typedef bf16 bf16x4 __attribute__((ext_vector_type(4)));
typedef bf16 bf16x8 __attribute__((ext_vector_type(8)));
typedef float floatx4 __attribute__((ext_vector_type(4)));

// ---- workspace offsets ----
// int-word offsets:
#define I_CNT  0             // 50176
#define I_ROW  50176         // 50432
#define I_BSUM 100608        // 256
#define I_BOFF 100864        // 256
#define I_CCUR 101120        // 256
#define I_CSR  101376        // 800000 -> ends word 901376
// byte offsets:
#define B_CREG 3605504       // 800000 * 8B records (6.4 MB)
#define B_XCB  10005504      // 6.4M bf16 column-blocked (12.8 MB)
#define B_ACB  22805504      // 6.4M bf16 column-blocked
#define B_H1   35605504      // 12.8M bf16 row-major (25.6 MB)
#define B_NV   61205504      // 50000 float4 (800 KB)
#define B_WT1  62005504      // 65536 bf16
#define B_WT2  62136576      // 65536 bf16
#define B_P    62267648      // 50176 fp32
#define B_Q    62468352      // 50176 fp32
// end ~62.7 MB

__global__ __launch_bounds__(256) void count_kernel(const int* __restrict__ dst,
                                                    int* __restrict__ cnt, int n) {
    int i = blockIdx.x * blockDim.x + threadIdx.x;
    if (i < n) atomicAdd(&cnt[dst[i]], 1);
}

__global__ __launch_bounds__(256) void scan1_kernel(const int* __restrict__ cnt,
                                                    int* __restrict__ bsum) {
    __shared__ int s[256];
    int t = threadIdx.x;
    int i = blockIdx.x * 256 + t;
    s[t] = (i < NN) ? cnt[i] : 0;
    __syncthreads();
    for (int o = 128; o > 0; o >>= 1) {
        if (t < o) s[t] += s[t + o];
        __syncthreads();
    }
    if (t == 0) bsum[blockIdx.x] = s[0];
}

__global__ __launch_bounds__(256) void scan2_kernel(const int* __restrict__ bsum,
                                                    int* __restrict__ boff) {
    __shared__ int s[256];
    int t = threadIdx.x;
    s[t] = (t < NB) ? bsum[t] : 0;
    __syncthreads();
    for (int o = 1; o < 256; o <<= 1) {
        int u = (t >= o) ? s[t - o] : 0;
        __syncthreads();
        s[t] += u;
        __syncthreads();
    }
    if (t < NB) boff[t] = (t == 0) ? 0 : s[t - 1];
}

__global__ __launch_bounds__(256) void scan3_kernel(const int* __restrict__ cnt,
                                                    const int* __restrict__ boff,
                                                    int* __restrict__ rowstart,
                                                    int* __restrict__ ccur) {
    __shared__ int s[256];
    int t = threadIdx.x;
    int i = blockIdx.x * 256 + t;
    int v = (i < NN) ? cnt[i] : 0;
    s[t] = v;
    __syncthreads();
    for (int o = 1; o < 256; o <<= 1) {
        int u = (t >= o) ? s[t - o] : 0;
        __syncthreads();
        s[t] += u;
        __syncthreads();
    }
    int excl = boff[blockIdx.x] + s[t] - v;
    if (i < NN) rowstart[i] = excl;
    if (i == NN - 1) rowstart[NN] = EM;
    if (t == 0) ccur[blockIdx.x] = boff[blockIdx.x];
}

// pass A: LDS-sort 4096 edges by coarse bucket (dst>>8), flush bucket-grouped
// 8B (src,dst) records into per-bucket regions of creg.
__global__ __launch_bounds__(256) void bin_kernel(const int* __restrict__ src,
                                                  const int* __restrict__ dst,
                                                  int* __restrict__ ccur,
                                                  unsigned long long* __restrict__ creg) {
    __shared__ int hist[NB];
    __shared__ int cnt2[NB];
    __shared__ int goff[NB];
    __shared__ int base[256];
    __shared__ unsigned long long sorted[RPB];
    int t = threadIdx.x;
    int e0 = blockIdx.x * RPB;
    int nrec = EM - e0; if (nrec > RPB) nrec = RPB;

    for (int i = t; i < NB; i += 256) { hist[i] = 0; cnt2[i] = 0; }
    __syncthreads();

    int myb[RPB / 256];
    unsigned long long myrec[RPB / 256];
#pragma unroll
    for (int j = 0; j < RPB / 256; ++j) {
        int idx = j * 256 + t;
        if (idx < nrec) {
            int s = src[e0 + idx], d = dst[e0 + idx];
            myb[j] = d >> 8;
            myrec[j] = ((unsigned long long)(unsigned)d << 32) | (unsigned)s;
            atomicAdd(&hist[myb[j]], 1);
        } else myb[j] = -1;
    }
    __syncthreads();

    base[t] = (t < NB) ? hist[t] : 0;
    __syncthreads();
    for (int o = 1; o < 256; o <<= 1) {
        int u = (t >= o) ? base[t - o] : 0;
        __syncthreads();
        base[t] += u;
        __syncthreads();
    }

    if (t < NB && hist[t] > 0) goff[t] = atomicAdd(&ccur[t], hist[t]);
#pragma unroll
    for (int j = 0; j < RPB / 256; ++j) {
        if (myb[j] >= 0) {
            int rk = atomicAdd(&cnt2[myb[j]], 1);
            sorted[base[myb[j]] - hist[myb[j]] + rk] = myrec[j];
        }
    }
    __syncthreads();

#pragma unroll
    for (int j = 0; j < RPB / 256; ++j) {
        int idx = j * 256 + t;
        if (idx < nrec) {
            unsigned long long rec = sorted[idx];
            int b = (int)(rec >> 40);
            int exb = base[b] - hist[b];
            creg[(size_t)goff[b] + (idx - exb)] = rec;
        }
    }
}

// pass B: one block per coarse bucket; LDS cursors position edges within the
// bucket's exclusively-owned csr range.
__global__ __launch_bounds__(256) void binsort_kernel(
    const unsigned long long* __restrict__ creg,
    const int* __restrict__ rowstart, int* __restrict__ csr) {
    __shared__ int lcur[256];
    int t = threadIdx.x;
    int node0 = blockIdx.x * 256;
    int nodes = NN - node0; if (nodes > 256) nodes = 256;
    if (t < nodes) lcur[t] = rowstart[node0 + t];
    __syncthreads();
    int beg = rowstart[node0];
    int end = rowstart[node0 + nodes];
    for (int i = beg + t; i < end; i += 256) {
        unsigned long long rec = creg[i];
        int s = (int)(rec & 0xffffffffu);
        int d = (int)(rec >> 32);
        int pos = atomicAdd(&lcur[d - node0], 1);
        csr[pos] = s;
    }
}

// fused conversions: blocks [0,XCONV_BLOCKS) -> x fp32 row-major to bf16
// column-blocked xcb[blk][node][16]; remaining 256 blocks -> Wt1/Wt2.
__global__ __launch_bounds__(256) void conv_kernel(
    const float* __restrict__ x, bf16* __restrict__ xcb,
    const float* __restrict__ W1s, const float* __restrict__ W1n,
    const float* __restrict__ W2n, const float* __restrict__ W2s,
    bf16* __restrict__ Wt1, bf16* __restrict__ Wt2) {
    if (blockIdx.x < XCONV_BLOCKS) {
        int i = blockIdx.x * 256 + threadIdx.x;   // quad index
        float4 v = ((const float4*)x)[i];
        int e = i * 4;
        int n = e >> 7, c = e & 127;
        bf16x4 o;
        o[0] = (bf16)v.x; o[1] = (bf16)v.y; o[2] = (bf16)v.z; o[3] = (bf16)v.w;
        *(bf16x4*)(xcb + ((size_t)(c >> 4) * NN + n) * 16 + (c & 15)) = o;
    } else {
        int i = (blockIdx.x - XCONV_BLOCKS) * 256 + threadIdx.x;
        if (i >= 65536) return;
        int n = i >> 8, k = i & 255;
        float w1 = (k < 128) ? W1s[k * 256 + n] : W1n[(k - 128) * 256 + n];
        Wt1[i] = (bf16)w1;
        float w2 = (n < 128) ? W2n[k * 128 + n] : W2s[k * 128 + (n - 128)];
        Wt2[i] = (bf16)w2;
    }
}

// column-blocked gather: cblk = blockIdx%8 (XCD-locality). Half-wave (32
// lanes) per node, 2 lanes/edge (16 edges in flight), 8 nodes per half.
__global__ __launch_bounds__(256) void gather1_kernel(const bf16* __restrict__ xcb,
                                                      const int* __restrict__ rowstart,
                                                      const int* __restrict__ csr,
                                                      bf16* __restrict__ aggcb) {
    int cblk = blockIdx.x & 7;
    int chunk = blockIdx.x >> 3;
    int lane = threadIdx.x & 63;
    int wave = threadIdx.x >> 6;
    int half = lane >> 5;
    int hl = lane & 31;
    int l2 = hl >> 1, h = hl & 1;
    const bf16* slice = xcb + (size_t)cblk * NN * 16;
    bf16* oslice = aggcb + (size_t)cblk * NN * 16;
    int nodebase = chunk * 64 + wave * 16 + half * 8;
#pragma unroll
    for (int j = 0; j < 8; ++j) {
        int n = nodebase + j;
        if (n >= NN) return;
        int beg = rowstart[n], end = rowstart[n + 1];
        float acc[8] = {0.f, 0.f, 0.f, 0.f, 0.f, 0.f, 0.f, 0.f};
        for (int i = beg + l2; i < end; i += 16) {
            int s = csr[i];
            bf16x8 v = *(const bf16x8*)(slice + (size_t)s * 16 + h * 8);
#pragma unroll
            for (int u = 0; u < 8; ++u) acc[u] += (float)v[u];
        }
#pragma unroll
        for (int m = 2; m <= 16; m <<= 1)
#pragma unroll
            for (int u = 0; u < 8; ++u) acc[u] += __shfl_xor(acc[u], m);
        if (l2 == 0) {
            int deg = end - beg;
            float inv = 1.0f / (float)(deg > 0 ? deg : 1);
            bf16x8 o;
#pragma unroll
            for (int u = 0; u < 8; ++u) o[u] = (bf16)(acc[u] * inv);
            *(bf16x8*)(oslice + (size_t)n * 16 + h * 8) = o;
        }
    }
}

// h1 = relu([x | agg1] @ Wt1^T + b1) -> bf16 row-major. B in registers,
// A streamed from the column-blocked tables.
__global__ __launch_bounds__(256) void gemm1_kernel(
    const bf16* __restrict__ xcb, const bf16* __restrict__ aggcb,
    const bf16* __restrict__ Wt, const float* __restrict__ b1,
    bf16* __restrict__ h1b) {
    int w = threadIdx.x >> 6;
    int lane = threadIdx.x & 63;
    int r = lane & 15, quad = lane >> 4;
    int colbase = w * 64;

    bf16x8 bfr[4][8];
#pragma unroll
    for (int t = 0; t < 4; ++t)
#pragma unroll
        for (int kk = 0; kk < 8; ++kk)
            bfr[t][kk] = *(const bf16x8*)(Wt + (size_t)(colbase + t * 16 + r) * 256
                                          + kk * 32 + quad * 8);
    float bb[4];
#pragma unroll
    for (int t = 0; t < 4; ++t) bb[t] = b1[colbase + t * 16 + r];

    int blk = quad >> 1;          // within-pair block select
    int off = (quad & 1) * 8;
    for (int tile = blockIdx.x; tile < MTILES; tile += GEMM_GRID) {
        int m0 = tile * 16;
        int row = m0 + r;
        bf16x8 a[8];
#pragma unroll
        for (int kk = 0; kk < 4; ++kk)
            a[kk] = *(const bf16x8*)(xcb + ((size_t)(kk * 2 + blk) * NN + row) * 16 + off);
#pragma unroll
        for (int kk = 4; kk < 8; ++kk)
            a[kk] = *(const bf16x8*)(aggcb + ((size_t)((kk - 4) * 2 + blk) * NN + row) * 16 + off);
        floatx4 acc[4];
#pragma unroll
        for (int t = 0; t < 4; ++t) acc[t] = (floatx4){0.f, 0.f, 0.f, 0.f};
#pragma unroll
        for (int kk = 0; kk < 8; ++kk)
#pragma unroll
            for (int t = 0; t < 4; ++t)
                acc[t] = __builtin_amdgcn_mfma_f32_16x16x32_bf16(a[kk], bfr[t][kk],
                                                                 acc[t], 0, 0, 0);
        int mb = m0 + quad * 4;
#pragma unroll
        for (int t = 0; t < 4; ++t) {
            int col = colbase + t * 16 + r;
#pragma unroll
            for (int rr = 0; rr < 4; ++rr) {
                float v = acc[t][rr] + bb[t];
                v = v > 0.f ? v : 0.f;
                h1b[(size_t)(mb + rr) * 256 + col] = (bf16)v;
            }
        }
    }
}

// Fused gemm2: nodev[n] = {zp, zq, ps, qs}; zp=(h1@W2n)[n].wp[:128] etc.
__global__ __launch_bounds__(256) void gemm2_kernel(
    const bf16* __restrict__ h1b, const bf16* __restrict__ Wt,
    const float* __restrict__ b2, const float* __restrict__ wp,
    float4* __restrict__ nodev) {
    __shared__ float lp[4][16];
    __shared__ float lq[4][16];
    int w = threadIdx.x >> 6;
    int lane = threadIdx.x & 63;
    int r = lane & 15, quad = lane >> 4;
    int colbase = w * 64;

    bf16x8 bfr[4][8];
#pragma unroll
    for (int t = 0; t < 4; ++t)
#pragma unroll
        for (int kk = 0; kk < 8; ++kk)
            bfr[t][kk] = *(const bf16x8*)(Wt + (size_t)(colbase + t * 16 + r) * 256
                                          + kk * 32 + quad * 8);
    float bb[4], wA[4], wB[4];
#pragma unroll
    for (int t = 0; t < 4; ++t) {
        int col = colbase + t * 16 + r;
        if (w < 2) {
            bb[t] = 0.f;
            wA[t] = wp[col];
            wB[t] = wp[128 + col];
        } else {
            int c2 = col - 128;
            bb[t] = b2[c2];
            wA[t] = wp[c2];
            wB[t] = wp[128 + c2];
        }
    }

    for (int tile = blockIdx.x; tile < MTILES; tile += GEMM_GRID) {
        int m0 = tile * 16;
        int row = m0 + r;
        bf16x8 a[8];
#pragma unroll
        for (int kk = 0; kk < 8; ++kk)
            a[kk] = *(const bf16x8*)(h1b + (size_t)row * 256 + kk * 32 + quad * 8);
        floatx4 acc[4];
#pragma unroll
        for (int t = 0; t < 4; ++t) acc[t] = (floatx4){0.f, 0.f, 0.f, 0.f};
#pragma unroll
        for (int kk = 0; kk < 8; ++kk)
#pragma unroll
            for (int t = 0; t < 4; ++t)
                acc[t] = __builtin_amdgcn_mfma_f32_16x16x32_bf16(a[kk], bfr[t][kk],
                                                                 acc[t], 0, 0, 0);
        float pacc[4], qacc[4];
#pragma unroll
        for (int rr = 0; rr < 4; ++rr) {
            float pr = 0.f, qr = 0.f;
#pragma unroll
            for (int t = 0; t < 4; ++t) {
                float v = acc[t][rr] + bb[t];
                pr += v * wA[t];
                qr += v * wB[t];
            }
            pacc[rr] = pr;
            qacc[rr] = qr;
        }
#pragma unroll
        for (int m = 1; m <= 8; m <<= 1) {
#pragma unroll
            for (int rr = 0; rr < 4; ++rr) {
                pacc[rr] += __shfl_xor(pacc[rr], m);
                qacc[rr] += __shfl_xor(qacc[rr], m);
            }
        }
        if (r == 0) {
#pragma unroll
            for (int rr = 0; rr < 4; ++rr) {
                lp[w][quad * 4 + rr] = pacc[rr];
                lq[w][quad * 4 + rr] = qacc[rr];
            }
        }
        __syncthreads();
        if (threadIdx.x < 16) {
            int rw = threadIdx.x;
            float4 o;
            o.x = lp[0][rw] + lp[1][rw];
            o.y = lq[0][rw] + lq[1][rw];
            o.z = lp[2][rw] + lp[3][rw];
            o.w = lq[2][rw] + lq[3][rw];
            nodev[m0 + rw] = o;
        }
        __syncthreads();
    }
}

// scalar gather: p[n] = ps[n] + mean(zp[src]); q likewise. nodev is 800 KB.
__global__ __launch_bounds__(256) void gather2_kernel(
    const float4* __restrict__ nodev, const int* __restrict__ rowstart,
    const int* __restrict__ csr, float* __restrict__ p, float* __restrict__ q) {
    int t = threadIdx.x;
    int node = blockIdx.x * 16 + (t >> 4);
    if (node >= NN) return;
    int l = t & 15;
    int beg = rowstart[node], end = rowstart[node + 1];
    float pz = 0.f, qz = 0.f;
    for (int i = beg + l; i < end; i += 16) {
        float4 v = nodev[csr[i]];
        pz += v.x;
        qz += v.y;
    }
#pragma unroll
    for (int m = 8; m >= 1; m >>= 1) {
        pz += __shfl_xor(pz, m);
        qz += __shfl_xor(qz, m);
    }
    if (l == 0) {
        int deg = end - beg;
        float inv = 1.0f / (float)(deg > 0 ? deg : 1);
        float4 me = nodev[node];
        p[node] = me.z + pz * inv;
        q[node] = me.w + qz * inv;
    }
}

__global__ __launch_bounds__(256) void score_kernel(
    const int* __restrict__ psrc, const int* __restrict__ pdst,
    const int* __restrict__ nsrc, const int* __restrict__ ndst,
    const float* __restrict__ p, const float* __restrict__ q,
    const float* __restrict__ bp, float* __restrict__ out) {
    int i = blockIdx.x * blockDim.x + threadIdx.x;
    float b = bp[0];
    if (i < EPOS) {
        out[i] = p[psrc[i]] + q[pdst[i]] + b;
    } else if (i < EPOS + ENEG) {
        int j = i - EPOS;
        out[i] = p[nsrc[j]] + q[ndst[j]] + b;
    }
}

extern "C" void kernel_launch(void* const* d_in, const int* in_sizes, int n_in,
                              void* d_out, int out_size, void* d_ws, size_t ws_size,
                              hipStream_t stream) {
    const float* x    = (const float*)d_in[0];
    const int*   msrc = (const int*)d_in[1];
    const int*   mdst = (const int*)d_in[2];
    const int*   psrc = (const int*)d_in[3];
    const int*   pdst = (const int*)d_in[4];
    const int*   nsrc = (const int*)d_in[5];
    const int*   ndst = (const int*)d_in[6];
    const float* W1s  = (const float*)d_in[7];
    const float* W1n  = (const float*)d_in[8];
    const float* b1   = (const float*)d_in[9];
    const float* W2s  = (const float*)d_in[10];
    const float* W2n  = (const float*)d_in[11];
    const float* b2   = (const float*)d_in[12];
    const float* wp   = (const float*)d_in[13];
    const float* bp   = (const float*)d_in[14];

    char* ws = (char*)d_ws;
    int*   cnt      = (int*)ws + I_CNT;
    int*   rowstart = (int*)ws + I_ROW;
    int*   bsum     = (int*)ws + I_BSUM;
    int*   boff     = (int*)ws + I_BOFF;
    int*   ccur     = (int*)ws + I_CCUR;
    int*   csr_src  = (int*)ws + I_CSR;
    unsigned long long* creg = (unsigned long long*)(ws + B_CREG);
    bf16*   xcb   = (bf16*)(ws + B_XCB);
    bf16*   aggcb = (bf16*)(ws + B_ACB);
    bf16*   h1b   = (bf16*)(ws + B_H1);
    float4* nodev = (float4*)(ws + B_NV);
    bf16*   Wt1   = (bf16*)(ws + B_WT1);
    bf16*   Wt2   = (bf16*)(ws + B_WT2);
    float*  p     = (float*)(ws + B_P);
    float*  q     = (float*)(ws + B_Q);
    float*  out   = (float*)d_out;

    hipMemsetAsync(cnt, 0, 50176 * sizeof(int), stream);

    count_kernel<<<(EM + 255) / 256, 256, 0, stream>>>(mdst, cnt, EM);
    scan1_kernel<<<NB, 256, 0, stream>>>(cnt, bsum);
    scan2_kernel<<<1, 256, 0, stream>>>(bsum, boff);
    scan3_kernel<<<NB, 256, 0, stream>>>(cnt, boff, rowstart, ccur);
    bin_kernel<<<(EM + RPB - 1) / RPB, 256, 0, stream>>>(msrc, mdst, ccur, creg);
    binsort_kernel<<<NB, 256, 0, stream>>>(creg, rowstart, csr_src);

    conv_kernel<<<XCONV_BLOCKS + 256, 256, 0, stream>>>(x, xcb, W1s, W1n, W2n, W2s,
                                                        Wt1, Wt2);

    gather1_kernel<<<((NN + 63) / 64) * 8, 256, 0, stream>>>(xcb, rowstart, csr_src,
                                                             aggcb);
    gemm1_kernel<<<GEMM_GRID, 256, 0, stream>>>(xcb, aggcb, Wt1, b1, h1b);
    gemm2_kernel<<<GEMM_GRID, 256, 0, stream>>>(h1b, Wt2, b2, wp, nodev);
    gather2_kernel<<<(NN + 15) / 16, 256, 0, stream>>>(nodev, rowstart, csr_src, p, q);
    score_kernel<<<(EPOS + ENEG + 255) / 256, 256, 0, stream>>>(
        psrc, pdst, nsrc, ndst, p, q, bp, out);
}

// Round 9
// 263.720 us; speedup vs baseline: 1.1455x; 1.1455x over previous
//
#include <hip/hip_runtime.h>

// GraphSAGE 2-layer + edge scorer, MI355X.
// R9: R8's column-blocked gather REVERTED (8x edge-loop duplication made it
// execution-bound: 80 us, VALU 40%). Back to row-major gather but with
// bf16x8 loads (16 B/lane) and 4 edges in flight per wave (quad-parallel):
// 4x fewer wave-issues + 4x MLP vs R7's bf16x2 form.
// Kept: scalar gather2 via wp-dot commute (R7), binned CSR build (R6),
// B-in-registers GEMMs (R5), mean(h1[src])@W2n == mean((h1@W2n)[src]).

#define NN 50000
#define EM 800000
#define EPOS 200000
#define ENEG 200000
#define NB 196            // scan blocks / coarse buckets: 196*256 >= NN
#define RPB 4096          // records per bin_kernel block
#define MTILES 3125       // 50000 / 16 exactly
#define GEMM_GRID 512
#define XCONV_BLOCKS 6250 // NN*128/4/256

typedef __bf16 bf16;
typedef bf16 bf16x2 __attribute__((ext_vector_type(2)));
typedef bf16 bf16x4 __attribute__((ext_vector_type(4)));
typedef bf16 bf16x8 __attribute__((ext_vector_type(8)));
typedef float floatx4 __attribute__((ext_vector_type(4)));

// ---- workspace offsets ----
// int-word offsets:
#define I_CNT  0             // 50176
#define I_ROW  50176         // 50432
#define I_BSUM 100608        // 256
#define I_BOFF 100864        // 256
#define I_CCUR 101120        // 256
#define I_CSR  101376        // 800000 -> ends word 901376
// byte offsets:
#define B_CREG 3605504       // 800000 * 8B records (6.4 MB)
#define B_XB   10005504      // 6.4M bf16 row-major (12.8 MB)
#define B_AGG1 22805504      // 6.4M bf16 row-major
#define B_H1   35605504      // 12.8M bf16 row-major (25.6 MB)
#define B_NV   61205504      // 50000 float4 (800 KB)
#define B_WT1  62005504      // 65536 bf16
#define B_WT2  62136576      // 65536 bf16
#define B_P    62267648      // 50176 fp32
#define B_Q    62468352      // 50176 fp32
// end ~62.7 MB

__global__ __launch_bounds__(256) void count_kernel(const int* __restrict__ dst,
                                                    int* __restrict__ cnt, int n) {
    int i = blockIdx.x * blockDim.x + threadIdx.x;
    if (i < n) atomicAdd(&cnt[dst[i]], 1);
}

__global__ __launch_bounds__(256) void scan1_kernel(const int* __restrict__ cnt,
                                                    int* __restrict__ bsum) {
    __shared__ int s[256];
    int t = threadIdx.x;
    int i = blockIdx.x * 256 + t;
    s[t] = (i < NN) ? cnt[i] : 0;
    __syncthreads();
    for (int o = 128; o > 0; o >>= 1) {
        if (t < o) s[t] += s[t + o];
        __syncthreads();
    }
    if (t == 0) bsum[blockIdx.x] = s[0];
}

__global__ __launch_bounds__(256) void scan2_kernel(const int* __restrict__ bsum,
                                                    int* __restrict__ boff) {
    __shared__ int s[256];
    int t = threadIdx.x;
    s[t] = (t < NB) ? bsum[t] : 0;
    __syncthreads();
    for (int o = 1; o < 256; o <<= 1) {
        int u = (t >= o) ? s[t - o] : 0;
        __syncthreads();
        s[t] += u;
        __syncthreads();
    }
    if (t < NB) boff[t] = (t == 0) ? 0 : s[t - 1];
}

__global__ __launch_bounds__(256) void scan3_kernel(const int* __restrict__ cnt,
                                                    const int* __restrict__ boff,
                                                    int* __restrict__ rowstart,
                                                    int* __restrict__ ccur) {
    __shared__ int s[256];
    int t = threadIdx.x;
    int i = blockIdx.x * 256 + t;
    int v = (i < NN) ? cnt[i] : 0;
    s[t] = v;
    __syncthreads();
    for (int o = 1; o < 256; o <<= 1) {
        int u = (t >= o) ? s[t - o] : 0;
        __syncthreads();
        s[t] += u;
        __syncthreads();
    }
    int excl = boff[blockIdx.x] + s[t] - v;
    if (i < NN) rowstart[i] = excl;
    if (i == NN - 1) rowstart[NN] = EM;
    if (t == 0) ccur[blockIdx.x] = boff[blockIdx.x];
}

// pass A: LDS-sort 4096 edges by coarse bucket (dst>>8), flush bucket-grouped
// 8B (src,dst) records into per-bucket regions of creg.
__global__ __launch_bounds__(256) void bin_kernel(const int* __restrict__ src,
                                                  const int* __restrict__ dst,
                                                  int* __restrict__ ccur,
                                                  unsigned long long* __restrict__ creg) {
    __shared__ int hist[NB];
    __shared__ int cnt2[NB];
    __shared__ int goff[NB];
    __shared__ int base[256];
    __shared__ unsigned long long sorted[RPB];
    int t = threadIdx.x;
    int e0 = blockIdx.x * RPB;
    int nrec = EM - e0; if (nrec > RPB) nrec = RPB;

    for (int i = t; i < NB; i += 256) { hist[i] = 0; cnt2[i] = 0; }
    __syncthreads();

    int myb[RPB / 256];
    unsigned long long myrec[RPB / 256];
#pragma unroll
    for (int j = 0; j < RPB / 256; ++j) {
        int idx = j * 256 + t;
        if (idx < nrec) {
            int s = src[e0 + idx], d = dst[e0 + idx];
            myb[j] = d >> 8;
            myrec[j] = ((unsigned long long)(unsigned)d << 32) | (unsigned)s;
            atomicAdd(&hist[myb[j]], 1);
        } else myb[j] = -1;
    }
    __syncthreads();

    base[t] = (t < NB) ? hist[t] : 0;
    __syncthreads();
    for (int o = 1; o < 256; o <<= 1) {
        int u = (t >= o) ? base[t - o] : 0;
        __syncthreads();
        base[t] += u;
        __syncthreads();
    }

    if (t < NB && hist[t] > 0) goff[t] = atomicAdd(&ccur[t], hist[t]);
#pragma unroll
    for (int j = 0; j < RPB / 256; ++j) {
        if (myb[j] >= 0) {
            int rk = atomicAdd(&cnt2[myb[j]], 1);
            sorted[base[myb[j]] - hist[myb[j]] + rk] = myrec[j];
        }
    }
    __syncthreads();

#pragma unroll
    for (int j = 0; j < RPB / 256; ++j) {
        int idx = j * 256 + t;
        if (idx < nrec) {
            unsigned long long rec = sorted[idx];
            int b = (int)(rec >> 40);
            int exb = base[b] - hist[b];
            creg[(size_t)goff[b] + (idx - exb)] = rec;
        }
    }
}

// pass B: one block per coarse bucket; LDS cursors position edges within the
// bucket's exclusively-owned csr range.
__global__ __launch_bounds__(256) void binsort_kernel(
    const unsigned long long* __restrict__ creg,
    const int* __restrict__ rowstart, int* __restrict__ csr) {
    __shared__ int lcur[256];
    int t = threadIdx.x;
    int node0 = blockIdx.x * 256;
    int nodes = NN - node0; if (nodes > 256) nodes = 256;
    if (t < nodes) lcur[t] = rowstart[node0 + t];
    __syncthreads();
    int beg = rowstart[node0];
    int end = rowstart[node0 + nodes];
    for (int i = beg + t; i < end; i += 256) {
        unsigned long long rec = creg[i];
        int s = (int)(rec & 0xffffffffu);
        int d = (int)(rec >> 32);
        int pos = atomicAdd(&lcur[d - node0], 1);
        csr[pos] = s;
    }
}

// fused conversions: blocks [0,XCONV_BLOCKS) -> x fp32 to bf16 row-major;
// remaining 256 blocks -> Wt1/Wt2.
__global__ __launch_bounds__(256) void conv_kernel(
    const float* __restrict__ x, bf16* __restrict__ xb,
    const float* __restrict__ W1s, const float* __restrict__ W1n,
    const float* __restrict__ W2n, const float* __restrict__ W2s,
    bf16* __restrict__ Wt1, bf16* __restrict__ Wt2) {
    if (blockIdx.x < XCONV_BLOCKS) {
        int i = blockIdx.x * 256 + threadIdx.x;
        float4 v = ((const float4*)x)[i];
        bf16x4 o;
        o[0] = (bf16)v.x; o[1] = (bf16)v.y; o[2] = (bf16)v.z; o[3] = (bf16)v.w;
        *(bf16x4*)(xb + (size_t)i * 4) = o;
    } else {
        int i = (blockIdx.x - XCONV_BLOCKS) * 256 + threadIdx.x;
        if (i >= 65536) return;
        int n = i >> 8, k = i & 255;
        float w1 = (k < 128) ? W1s[k * 256 + n] : W1n[(k - 128) * 256 + n];
        Wt1[i] = (bf16)w1;
        float w2 = (n < 128) ? W2n[k * 128 + n] : W2s[k * 128 + (n - 128)];
        Wt2[i] = (bf16)w2;
    }
}

// one wave per node, 4 edges in flight (quad-parallel), bf16x8 per lane
// (16 lanes span 128 cols, 16 B/lane). 2-level shuffle reduce over quads.
__global__ __launch_bounds__(256) void gather1_kernel(const bf16* __restrict__ feat,
                                                      const int* __restrict__ rowstart,
                                                      const int* __restrict__ csr,
                                                      bf16* __restrict__ agg) {
    int node = (blockIdx.x * 256 + threadIdx.x) >> 6;
    if (node >= NN) return;
    int lane = threadIdx.x & 63;
    int q = lane >> 4, r = lane & 15;
    int c = r * 8;
    int beg = rowstart[node], end = rowstart[node + 1];
    float acc[8] = {0.f, 0.f, 0.f, 0.f, 0.f, 0.f, 0.f, 0.f};
    for (int i = beg + q; i < end; i += 4) {
        int s = csr[i];
        bf16x8 v = *(const bf16x8*)(feat + (size_t)s * 128 + c);
#pragma unroll
        for (int u = 0; u < 8; ++u) acc[u] += (float)v[u];
    }
#pragma unroll
    for (int m = 16; m <= 32; m <<= 1)
#pragma unroll
        for (int u = 0; u < 8; ++u) acc[u] += __shfl_xor(acc[u], m);
    if (q == 0) {
        int deg = end - beg;
        float inv = 1.0f / (float)(deg > 0 ? deg : 1);
        bf16x8 o;
#pragma unroll
        for (int u = 0; u < 8; ++u) o[u] = (bf16)(acc[u] * inv);
        *(bf16x8*)(agg + (size_t)node * 128 + c) = o;
    }
}

// h1 = relu([xb | agg1b] @ Wt1^T + b1) -> bf16. B in registers, A streamed.
__global__ __launch_bounds__(256) void gemm1_kernel(
    const bf16* __restrict__ xb, const bf16* __restrict__ aggb,
    const bf16* __restrict__ Wt, const float* __restrict__ b1,
    bf16* __restrict__ h1b) {
    int w = threadIdx.x >> 6;
    int lane = threadIdx.x & 63;
    int r = lane & 15, quad = lane >> 4;
    int colbase = w * 64;

    bf16x8 bfr[4][8];
#pragma unroll
    for (int t = 0; t < 4; ++t)
#pragma unroll
        for (int kk = 0; kk < 8; ++kk)
            bfr[t][kk] = *(const bf16x8*)(Wt + (size_t)(colbase + t * 16 + r) * 256
                                          + kk * 32 + quad * 8);
    float bb[4];
#pragma unroll
    for (int t = 0; t < 4; ++t) bb[t] = b1[colbase + t * 16 + r];

    for (int tile = blockIdx.x; tile < MTILES; tile += GEMM_GRID) {
        int m0 = tile * 16;
        int row = m0 + r;
        bf16x8 a[8];
#pragma unroll
        for (int kk = 0; kk < 4; ++kk)
            a[kk] = *(const bf16x8*)(xb + (size_t)row * 128 + kk * 32 + quad * 8);
#pragma unroll
        for (int kk = 4; kk < 8; ++kk)
            a[kk] = *(const bf16x8*)(aggb + (size_t)row * 128 + (kk - 4) * 32 + quad * 8);
        floatx4 acc[4];
#pragma unroll
        for (int t = 0; t < 4; ++t) acc[t] = (floatx4){0.f, 0.f, 0.f, 0.f};
#pragma unroll
        for (int kk = 0; kk < 8; ++kk)
#pragma unroll
            for (int t = 0; t < 4; ++t)
                acc[t] = __builtin_amdgcn_mfma_f32_16x16x32_bf16(a[kk], bfr[t][kk],
                                                                 acc[t], 0, 0, 0);
        int mb = m0 + quad * 4;
#pragma unroll
        for (int t = 0; t < 4; ++t) {
            int col = colbase + t * 16 + r;
#pragma unroll
            for (int rr = 0; rr < 4; ++rr) {
                float v = acc[t][rr] + bb[t];
                v = v > 0.f ? v : 0.f;
                h1b[(size_t)(mb + rr) * 256 + col] = (bf16)v;
            }
        }
    }
}

// Fused gemm2: nodev[n] = {zp, zq, ps, qs}; zp=(h1@W2n)[n].wp[:128] etc.
__global__ __launch_bounds__(256) void gemm2_kernel(
    const bf16* __restrict__ h1b, const bf16* __restrict__ Wt,
    const float* __restrict__ b2, const float* __restrict__ wp,
    float4* __restrict__ nodev) {
    __shared__ float lp[4][16];
    __shared__ float lq[4][16];
    int w = threadIdx.x >> 6;
    int lane = threadIdx.x & 63;
    int r = lane & 15, quad = lane >> 4;
    int colbase = w * 64;

    bf16x8 bfr[4][8];
#pragma unroll
    for (int t = 0; t < 4; ++t)
#pragma unroll
        for (int kk = 0; kk < 8; ++kk)
            bfr[t][kk] = *(const bf16x8*)(Wt + (size_t)(colbase + t * 16 + r) * 256
                                          + kk * 32 + quad * 8);
    float bb[4], wA[4], wB[4];
#pragma unroll
    for (int t = 0; t < 4; ++t) {
        int col = colbase + t * 16 + r;
        if (w < 2) {
            bb[t] = 0.f;
            wA[t] = wp[col];
            wB[t] = wp[128 + col];
        } else {
            int c2 = col - 128;
            bb[t] = b2[c2];
            wA[t] = wp[c2];
            wB[t] = wp[128 + c2];
        }
    }

    for (int tile = blockIdx.x; tile < MTILES; tile += GEMM_GRID) {
        int m0 = tile * 16;
        int row = m0 + r;
        bf16x8 a[8];
#pragma unroll
        for (int kk = 0; kk < 8; ++kk)
            a[kk] = *(const bf16x8*)(h1b + (size_t)row * 256 + kk * 32 + quad * 8);
        floatx4 acc[4];
#pragma unroll
        for (int t = 0; t < 4; ++t) acc[t] = (floatx4){0.f, 0.f, 0.f, 0.f};
#pragma unroll
        for (int kk = 0; kk < 8; ++kk)
#pragma unroll
            for (int t = 0; t < 4; ++t)
                acc[t] = __builtin_amdgcn_mfma_f32_16x16x32_bf16(a[kk], bfr[t][kk],
                                                                 acc[t], 0, 0, 0);
        float pacc[4], qacc[4];
#pragma unroll
        for (int rr = 0; rr < 4; ++rr) {
            float pr = 0.f, qr = 0.f;
#pragma unroll
            for (int t = 0; t < 4; ++t) {
                float v = acc[t][rr] + bb[t];
                pr += v * wA[t];
                qr += v * wB[t];
            }
            pacc[rr] = pr;
            qacc[rr] = qr;
        }
#pragma unroll
        for (int m = 1; m <= 8; m <<= 1) {
#pragma unroll
            for (int rr = 0; rr < 4; ++rr) {
                pacc[rr] += __shfl_xor(pacc[rr], m);
                qacc[rr] += __shfl_xor(qacc[rr], m);
            }
        }
        if (r == 0) {
#pragma unroll
            for (int rr = 0; rr < 4; ++rr) {
                lp[w][quad * 4 + rr] = pacc[rr];
                lq[w][quad * 4 + rr] = qacc[rr];
            }
        }
        __syncthreads();
        if (threadIdx.x < 16) {
            int rw = threadIdx.x;
            float4 o;
            o.x = lp[0][rw] + lp[1][rw];
            o.y = lq[0][rw] + lq[1][rw];
            o.z = lp[2][rw] + lp[3][rw];
            o.w = lq[2][rw] + lq[3][rw];
            nodev[m0 + rw] = o;
        }
        __syncthreads();
    }
}

// scalar gather: p[n] = ps[n] + mean(zp[src]); q likewise. nodev is 800 KB.
__global__ __launch_bounds__(256) void gather2_kernel(
    const float4* __restrict__ nodev, const int* __restrict__ rowstart,
    const int* __restrict__ csr, float* __restrict__ p, float* __restrict__ q) {
    int t = threadIdx.x;
    int node = blockIdx.x * 16 + (t >> 4);
    if (node >= NN) return;
    int l = t & 15;
    int beg = rowstart[node], end = rowstart[node + 1];
    float pz = 0.f, qz = 0.f;
    for (int i = beg + l; i < end; i += 16) {
        float4 v = nodev[csr[i]];
        pz += v.x;
        qz += v.y;
    }
#pragma unroll
    for (int m = 8; m >= 1; m >>= 1) {
        pz += __shfl_xor(pz, m);
        qz += __shfl_xor(qz, m);
    }
    if (l == 0) {
        int deg = end - beg;
        float inv = 1.0f / (float)(deg > 0 ? deg : 1);
        float4 me = nodev[node];
        p[node] = me.z + pz * inv;
        q[node] = me.w + qz * inv;
    }
}

__global__ __launch_bounds__(256) void score_kernel(
    const int* __restrict__ psrc, const int* __restrict__ pdst,
    const int* __restrict__ nsrc, const int* __restrict__ ndst,
    const float* __restrict__ p, const float* __restrict__ q,
    const float* __restrict__ bp, float* __restrict__ out) {
    int i = blockIdx.x * blockDim.x + threadIdx.x;
    float b = bp[0];
    if (i < EPOS) {
        out[i] = p[psrc[i]] + q[pdst[i]] + b;
    } else if (i < EPOS + ENEG) {
        int j = i - EPOS;
        out[i] = p[nsrc[j]] + q[ndst[j]] + b;
    }
}

extern "C" void kernel_launch(void* const* d_in, const int* in_sizes, int n_in,
                              void* d_out, int out_size, void* d_ws, size_t ws_size,
                              hipStream_t stream) {
    const float* x    = (const float*)d_in[0];
    const int*   msrc = (const int*)d_in[1];
    const int*   mdst = (const int*)d_in[2];
    const int*   psrc = (const int*)d_in[3];
    const int*   pdst = (const int*)d_in[4];
    const int*   nsrc = (const int*)d_in[5];
    const int*   ndst = (const int*)d_in[6];
    const float* W1s  = (const float*)d_in[7];
    const float* W1n  = (const float*)d_in[8];
    const float* b1   = (const float*)d_in[9];
    const float* W2s  = (const float*)d_in[10];
    const float* W2n  = (const float*)d_in[11];
    const float* b2   = (const float*)d_in[12];
    const float* wp   = (const float*)d_in[13];
    const float* bp   = (const float*)d_in[14];

    char* ws = (char*)d_ws;
    int*   cnt      = (int*)ws + I_CNT;
    int*   rowstart = (int*)ws + I_ROW;
    int*   bsum     = (int*)ws + I_BSUM;
    int*   boff     = (int*)ws + I_BOFF;
    int*   ccur     = (int*)ws + I_CCUR;
    int*   csr_src  = (int*)ws + I_CSR;
    unsigned long long* creg = (unsigned long long*)(ws + B_CREG);
    bf16*   xb    = (bf16*)(ws + B_XB);
    bf16*   agg1b = (bf16*)(ws + B_AGG1);
    bf16*   h1b   = (bf16*)(ws + B_H1);
    float4* nodev = (float4*)(ws + B_NV);
    bf16*   Wt1   = (bf16*)(ws + B_WT1);
    bf16*   Wt2   = (bf16*)(ws + B_WT2);
    float*  p     = (float*)(ws + B_P);
    float*  q     = (float*)(ws + B_Q);
    float*  out   = (float*)d_out;

    hipMemsetAsync(cnt, 0, 50176 * sizeof(int), stream);

    count_kernel<<<(EM + 255) / 256, 256, 0, stream>>>(mdst, cnt, EM);
    scan1_kernel<<<NB, 256, 0, stream>>>(cnt, bsum);
    scan2_kernel<<<1, 256, 0, stream>>>(bsum, boff);
    scan3_kernel<<<NB, 256, 0, stream>>>(cnt, boff, rowstart, ccur);
    bin_kernel<<<(EM + RPB - 1) / RPB, 256, 0, stream>>>(msrc, mdst, ccur, creg);
    binsort_kernel<<<NB, 256, 0, stream>>>(creg, rowstart, csr_src);

    conv_kernel<<<XCONV_BLOCKS + 256, 256, 0, stream>>>(x, xb, W1s, W1n, W2n, W2s,
                                                        Wt1, Wt2);

    gather1_kernel<<<(NN + 3) / 4, 256, 0, stream>>>(xb, rowstart, csr_src, agg1b);
    gemm1_kernel<<<GEMM_GRID, 256, 0, stream>>>(xb, agg1b, Wt1, b1, h1b);
    gemm2_kernel<<<GEMM_GRID, 256, 0, stream>>>(h1b, Wt2, b2, wp, nodev);
    gather2_kernel<<<(NN + 15) / 16, 256, 0, stream>>>(nodev, rowstart, csr_src, p, q);
    score_kernel<<<(EPOS + ENEG + 255) / 256, 256, 0, stream>>>(
        psrc, pdst, nsrc, ndst, p, q, bp, out);
}